// Round 1
// baseline (73740.491 us; speedup 1.0000x reference)
//
#include <hip/hip_runtime.h>
#include <hip/hip_bf16.h>

#define NWG 256
#define SEQ 2048
#define HID 512

typedef __attribute__((ext_vector_type(8))) short short8;
typedef __attribute__((ext_vector_type(4))) float f32x4;

__device__ inline short f2bf(float f) {
  union { float f; unsigned u; } v; v.f = f;
  unsigned r = v.u + 0x7FFFu + ((v.u >> 16) & 1u);
  return (short)(r >> 16);
}

__device__ inline float sigm(float x) { return 1.f / (1.f + __expf(-x)); }
__device__ inline float tanh_(float x) { float e = __expf(2.f * x); return 1.f - 2.f / (e + 1.f); }

__global__ void __launch_bounds__(128) lstm_kern(
    const float* __restrict__ X,
    const float* __restrict__ Wih,
    const float* __restrict__ Whh,
    const float* __restrict__ bih,
    const float* __restrict__ bhh,
    float* __restrict__ out,
    unsigned* __restrict__ bar,
    short* __restrict__ h1r,
    short* __restrict__ h2r) {
  // Per-WG: 4 hidden units -> 16 gate cols {g*512 + u0 + j}, K = 1024 ([x;h])
  __shared__ short Wlds[16][1032];   // W^T, bf16 bits; [col_loc][k], k<512 ih, >=512 hh; +8 pad breaks bank aliasing
  __shared__ float bsum[16];
  __shared__ float glds[16][44];     // gate pre-activations, col-major, padded

  const int tid = threadIdx.x;
  const int wg = blockIdx.x;
  const int layer = wg >> 7;         // 0: layer1 WGs, 1: layer2 WGs
  const int u0 = (wg & 127) * 4;

  // ---- one-time: stage weights (bf16) + fused bias into LDS ----
  {
    const int col_loc = tid >> 3;    // 0..15
    const int l8 = tid & 7;          // 0..7
    const int cg = (col_loc >> 2) * 512 + u0 + (col_loc & 3);
    const float* wi = Wih + ((size_t)layer * 2048 + cg) * 512;
    const float* wh = Whh + ((size_t)layer * 2048 + cg) * 512;
    for (int k0 = l8 * 4; k0 < 512; k0 += 32) {
      float4 a = *(const float4*)(wi + k0);
      Wlds[col_loc][k0 + 0] = f2bf(a.x); Wlds[col_loc][k0 + 1] = f2bf(a.y);
      Wlds[col_loc][k0 + 2] = f2bf(a.z); Wlds[col_loc][k0 + 3] = f2bf(a.w);
      float4 b = *(const float4*)(wh + k0);
      Wlds[col_loc][512 + k0 + 0] = f2bf(b.x); Wlds[col_loc][512 + k0 + 1] = f2bf(b.y);
      Wlds[col_loc][512 + k0 + 2] = f2bf(b.z); Wlds[col_loc][512 + k0 + 3] = f2bf(b.w);
    }
    if (tid < 16) {
      const int cg2 = (tid >> 2) * 512 + u0 + (tid & 3);
      bsum[tid] = bih[layer * 2048 + cg2] + bhh[layer * 2048 + cg2];
    }
  }
  __syncthreads();

  // MFMA lane mapping (16x16x32 bf16): A[m=lane&15][k=quad*8+j]; C/D col=lane&15, row=quad*4+reg
  const int lane = tid & 63;
  const int wid = tid >> 6;          // 2 waves: row-tiles m 0-15 / 16-31
  const int col = lane & 15;
  const int quad = lane >> 4;
  const int mo = wid * 16;
  const int m = mo + col;
  const int kj = quad * 8;

  const int eb = tid & 31;           // elementwise: batch
  const int eu = tid >> 5;           // elementwise: local unit 0..3
  float cst = 0.f;                   // cell state, fp32, register-resident

  unsigned* cnt = bar;
  unsigned* gen = bar + 32;          // separate cacheline
  short* wring = layer ? h2r : h1r;

  for (int p = 0; p <= SEQ; ++p) {
    const int tt = layer ? (p - 1) : p;
    const bool active = layer ? (p > 0) : (p < SEQ);

    if (active) {
      f32x4 acc = {0.f, 0.f, 0.f, 0.f};
      if (layer == 0) {
        // input half of K: X (fp32 in global, convert inline)
        const float* xrow = X + ((size_t)m * SEQ + tt) * 512 + kj;
        #pragma unroll
        for (int s = 0; s < 16; ++s) {
          const float* xp = xrow + s * 32;
          float4 f0 = *(const float4*)xp;
          float4 f1 = *(const float4*)(xp + 4);
          short8 a;
          a[0] = f2bf(f0.x); a[1] = f2bf(f0.y); a[2] = f2bf(f0.z); a[3] = f2bf(f0.w);
          a[4] = f2bf(f1.x); a[5] = f2bf(f1.y); a[6] = f2bf(f1.z); a[7] = f2bf(f1.w);
          short8 b = *(const short8*)&Wlds[col][s * 32 + kj];
          acc = __builtin_amdgcn_mfma_f32_16x16x32_bf16(a, b, acc, 0, 0, 0);
        }
      } else {
        // input half of K: h1 ring (bf16), slot tt&3 written by layer-1 last phase
        const short* xrow = h1r + ((size_t)(tt & 3) * 32 + m) * 512 + kj;
        #pragma unroll
        for (int s = 0; s < 16; ++s) {
          short8 a = *(const short8*)(xrow + s * 32);
          short8 b = *(const short8*)&Wlds[col][s * 32 + kj];
          acc = __builtin_amdgcn_mfma_f32_16x16x32_bf16(a, b, acc, 0, 0, 0);
        }
      }
      if (tt > 0) {  // recurrent half of K (h_{t-1}; zero at t==0 -> skip)
        const short* rring = layer ? h2r : h1r;
        const short* hrow = rring + ((size_t)((tt - 1) & 3) * 32 + m) * 512 + kj;
        #pragma unroll
        for (int s = 0; s < 16; ++s) {
          short8 a = *(const short8*)(hrow + s * 32);
          short8 b = *(const short8*)&Wlds[col][512 + s * 32 + kj];
          acc = __builtin_amdgcn_mfma_f32_16x16x32_bf16(a, b, acc, 0, 0, 0);
        }
      }
      const float bsv = bsum[col];
      const int b0 = mo + quad * 4;
      float4 gv;
      gv.x = acc[0] + bsv; gv.y = acc[1] + bsv; gv.z = acc[2] + bsv; gv.w = acc[3] + bsv;
      *(float4*)&glds[col][b0] = gv;
    }
    __syncthreads();
    if (active) {
      // col_loc = gate*4 + unit_local
      const float gi = glds[0 + eu][eb];
      const float gf = glds[4 + eu][eb];
      const float gg = glds[8 + eu][eb];
      const float go = glds[12 + eu][eb];
      const float iv = sigm(gi), fv = sigm(gf), gv2 = tanh_(gg), ov = sigm(go);
      cst = fv * cst + iv * gv2;
      const float hv = ov * tanh_(cst);
      wring[((size_t)(tt & 3) * 32 + eb) * 512 + (u0 + eu)] = f2bf(hv);
      if (layer) out[((size_t)eb * SEQ + tt) * 512 + (u0 + eu)] = hv;
    }
    // ---- grid barrier (monotone generation) ----
    __syncthreads();
    __threadfence();  // release: make ring/out writes agent-visible (cross-XCD)
    if (tid == 0) {
      unsigned prev = __hip_atomic_fetch_add(cnt, 1u, __ATOMIC_ACQ_REL, __HIP_MEMORY_SCOPE_AGENT);
      if (prev == NWG - 1) {
        __hip_atomic_store(cnt, 0u, __ATOMIC_RELAXED, __HIP_MEMORY_SCOPE_AGENT);
        __hip_atomic_store(gen, (unsigned)(p + 1), __ATOMIC_RELEASE, __HIP_MEMORY_SCOPE_AGENT);
      } else {
        while (__hip_atomic_load(gen, __ATOMIC_ACQUIRE, __HIP_MEMORY_SCOPE_AGENT) < (unsigned)(p + 1)) {
          __builtin_amdgcn_s_sleep(1);
        }
      }
    }
    __syncthreads();
    __threadfence();  // acquire: drop stale L1/L2 lines before reading peers' h
  }
}

extern "C" void kernel_launch(void* const* d_in, const int* in_sizes, int n_in,
                              void* d_out, int out_size, void* d_ws, size_t ws_size,
                              hipStream_t stream) {
  const float* X   = (const float*)d_in[0];
  const float* Wih = (const float*)d_in[1];
  const float* Whh = (const float*)d_in[2];
  const float* bih = (const float*)d_in[3];
  const float* bhh = (const float*)d_in[4];
  float* out = (float*)d_out;
  char* ws = (char*)d_ws;

  unsigned* bar = (unsigned*)ws;                       // cnt @0, gen @+128B
  short* h1r = (short*)(ws + 256);                     // [4][32][512] bf16 ring
  short* h2r = (short*)(ws + 256 + 4 * 32 * 512 * 2);  // [4][32][512] bf16 ring

  hipMemsetAsync(ws, 0, 256, stream);  // zero barrier state every launch

  void* args[] = {(void*)&X, (void*)&Wih, (void*)&Whh, (void*)&bih, (void*)&bhh,
                  (void*)&out, (void*)&bar, (void*)&h1r, (void*)&h2r};
  hipLaunchCooperativeKernel((void*)lstm_kern, dim3(NWG), dim3(128), args, 0, stream);
}

// Round 2
// 24039.780 us; speedup vs baseline: 3.0674x; 3.0674x over previous
//
#include <hip/hip_runtime.h>
#include <hip/hip_bf16.h>

#define NWG 256
#define SEQ 2048

typedef __attribute__((ext_vector_type(8))) short short8;
typedef __attribute__((ext_vector_type(4))) float f32x4;

__device__ inline short f2bf(float f) {
  union { float f; unsigned u; } v; v.f = f;
  unsigned r = v.u + 0x7FFFu + ((v.u >> 16) & 1u);
  return (short)(r >> 16);
}

__device__ inline float sigm(float x) { return 1.f / (1.f + __expf(-x)); }
__device__ inline float tanh_(float x) { float e = __expf(2.f * x); return 1.f - 2.f / (e + 1.f); }

__global__ void __launch_bounds__(128) lstm_kern(
    const float* __restrict__ X,
    const float* __restrict__ Wih,
    const float* __restrict__ Whh,
    const float* __restrict__ bih,
    const float* __restrict__ bhh,
    float* __restrict__ out,
    unsigned* __restrict__ flags,
    short* __restrict__ h1r,
    short* __restrict__ h2r) {
  // Per-WG: 4 hidden units -> 16 gate cols {g*512 + u0 + j}, K = 1024 ([x;h])
  __shared__ short Wlds[16][1032];   // W^T bf16; [col_loc][k], k<512 ih, >=512 hh
  __shared__ float bsum[16];
  __shared__ float glds[16][44];     // gate pre-activations, col-major, padded

  const int tid = threadIdx.x;
  const int wg = blockIdx.x;
  const int layer = wg >> 7;
  const int u0 = (wg & 127) * 4;

  // ---- one-time: stage weights (bf16) + fused bias into LDS ----
  {
    const int col_loc = tid >> 3;
    const int l8 = tid & 7;
    const int cg = (col_loc >> 2) * 512 + u0 + (col_loc & 3);
    const float* wi = Wih + ((size_t)layer * 2048 + cg) * 512;
    const float* wh = Whh + ((size_t)layer * 2048 + cg) * 512;
    for (int k0 = l8 * 4; k0 < 512; k0 += 32) {
      float4 a = *(const float4*)(wi + k0);
      Wlds[col_loc][k0 + 0] = f2bf(a.x); Wlds[col_loc][k0 + 1] = f2bf(a.y);
      Wlds[col_loc][k0 + 2] = f2bf(a.z); Wlds[col_loc][k0 + 3] = f2bf(a.w);
      float4 b = *(const float4*)(wh + k0);
      Wlds[col_loc][512 + k0 + 0] = f2bf(b.x); Wlds[col_loc][512 + k0 + 1] = f2bf(b.y);
      Wlds[col_loc][512 + k0 + 2] = f2bf(b.z); Wlds[col_loc][512 + k0 + 3] = f2bf(b.w);
    }
    if (tid < 16) {
      const int cg2 = (tid >> 2) * 512 + u0 + (tid & 3);
      bsum[tid] = bih[layer * 2048 + cg2] + bhh[layer * 2048 + cg2];
    }
  }
  __syncthreads();

  // MFMA mapping (16x16x32 bf16): A[m=lane&15][k=quad*8+j]; C/D col=lane&15, row=quad*4+reg
  const int lane = tid & 63;
  const int wid = tid >> 6;
  const int col = lane & 15;
  const int quad = lane >> 4;
  const int mo = wid * 16;
  const int m = mo + col;
  const int kj = quad * 8;

  // elementwise: threads 0..63: batch eb, unit-pair ep (2 adjacent units each)
  const int eb = tid & 31;
  const int ep = tid >> 5;           // 0..1 for tid<64
  float cst0 = 0.f, cst1 = 0.f;

  short* wring = layer ? h2r : h1r;
  unsigned* wringu = (unsigned*)wring;

  for (int p = 0; p <= SEQ; ++p) {
    const int tt = layer ? (p - 1) : p;
    const bool active = layer ? (p > 0) : (p < SEQ);

    if (active) {
      f32x4 acc = {0.f, 0.f, 0.f, 0.f};
      if (layer == 0) {
        const float* xrow = X + ((size_t)m * SEQ + tt) * 512 + kj;
        #pragma unroll
        for (int s = 0; s < 16; ++s) {
          const float* xp = xrow + s * 32;
          float4 f0 = *(const float4*)xp;
          float4 f1 = *(const float4*)(xp + 4);
          short8 a;
          a[0] = f2bf(f0.x); a[1] = f2bf(f0.y); a[2] = f2bf(f0.z); a[3] = f2bf(f0.w);
          a[4] = f2bf(f1.x); a[5] = f2bf(f1.y); a[6] = f2bf(f1.z); a[7] = f2bf(f1.w);
          short8 b = *(const short8*)&Wlds[col][s * 32 + kj];
          acc = __builtin_amdgcn_mfma_f32_16x16x32_bf16(a, b, acc, 0, 0, 0);
        }
      } else {
        const short* xrow = h1r + ((size_t)(tt & 3) * 32 + m) * 512 + kj;
        #pragma unroll
        for (int s = 0; s < 16; ++s) {
          short8 a = *(const short8*)(xrow + s * 32);
          short8 b = *(const short8*)&Wlds[col][s * 32 + kj];
          acc = __builtin_amdgcn_mfma_f32_16x16x32_bf16(a, b, acc, 0, 0, 0);
        }
      }
      if (tt > 0) {
        const short* rring = layer ? h2r : h1r;
        const short* hrow = rring + ((size_t)((tt - 1) & 3) * 32 + m) * 512 + kj;
        #pragma unroll
        for (int s = 0; s < 16; ++s) {
          short8 a = *(const short8*)(hrow + s * 32);
          short8 b = *(const short8*)&Wlds[col][512 + s * 32 + kj];
          acc = __builtin_amdgcn_mfma_f32_16x16x32_bf16(a, b, acc, 0, 0, 0);
        }
      }
      const float bsv = bsum[col];
      const int b0 = mo + quad * 4;
      float4 gv;
      gv.x = acc[0] + bsv; gv.y = acc[1] + bsv; gv.z = acc[2] + bsv; gv.w = acc[3] + bsv;
      *(float4*)&glds[col][b0] = gv;
    }
    __syncthreads();
    if (active && tid < 64) {
      const int e0 = 2 * ep;       // local unit 0
      float h0, h1;
      {
        const float gi = glds[0 + e0][eb], gf = glds[4 + e0][eb];
        const float gg = glds[8 + e0][eb], go = glds[12 + e0][eb];
        cst0 = sigm(gf) * cst0 + sigm(gi) * tanh_(gg);
        h0 = sigm(go) * tanh_(cst0);
      }
      {
        const float gi = glds[1 + e0][eb], gf = glds[5 + e0][eb];
        const float gg = glds[9 + e0][eb], go = glds[13 + e0][eb];
        cst1 = sigm(gf) * cst1 + sigm(gi) * tanh_(gg);
        h1 = sigm(go) * tanh_(cst1);
      }
      // packed 2xbf16, device-scope write-through store (no release fence needed)
      const unsigned pk = (unsigned)(unsigned short)f2bf(h0)
                        | ((unsigned)(unsigned short)f2bf(h1) << 16);
      __hip_atomic_store(&wringu[((size_t)(tt & 3) * 32 + eb) * 256 + (u0 >> 1) + ep],
                         pk, __ATOMIC_RELAXED, __HIP_MEMORY_SCOPE_AGENT);
      if (layer) {
        float2 o2; o2.x = h0; o2.y = h1;
        *(float2*)(out + ((size_t)eb * SEQ + tt) * 512 + u0 + 2 * ep) = o2;
      }
    }
    // ---- distributed-flag grid barrier ----
    __syncthreads();   // drains vmcnt: ring stores are LLC-visible past here
    if (tid == 0) {
      __hip_atomic_store(&flags[wg], (unsigned)(p + 1),
                         __ATOMIC_RELAXED, __HIP_MEMORY_SCOPE_AGENT);
    }
    const unsigned tgt = (unsigned)(p + 1);
    int done;
    do {
      const unsigned f0 = __hip_atomic_load(&flags[tid], __ATOMIC_RELAXED,
                                            __HIP_MEMORY_SCOPE_AGENT);
      const unsigned f1 = __hip_atomic_load(&flags[tid + 128], __ATOMIC_RELAXED,
                                            __HIP_MEMORY_SCOPE_AGENT);
      done = __syncthreads_and((int)(f0 >= tgt && f1 >= tgt));
    } while (!done);
    __builtin_amdgcn_fence(__ATOMIC_ACQUIRE, "agent");  // inv L1/L2 before reading peers' h
  }
}

extern "C" void kernel_launch(void* const* d_in, const int* in_sizes, int n_in,
                              void* d_out, int out_size, void* d_ws, size_t ws_size,
                              hipStream_t stream) {
  const float* X   = (const float*)d_in[0];
  const float* Wih = (const float*)d_in[1];
  const float* Whh = (const float*)d_in[2];
  const float* bih = (const float*)d_in[3];
  const float* bhh = (const float*)d_in[4];
  float* out = (float*)d_out;
  char* ws = (char*)d_ws;

  unsigned* flags = (unsigned*)ws;                       // 256 dwords
  short* h1r = (short*)(ws + 1024);                      // [4][32][512] bf16 ring
  short* h2r = (short*)(ws + 1024 + 4 * 32 * 512 * 2);   // [4][32][512] bf16 ring

  hipMemsetAsync(ws, 0, 1024, stream);  // zero flags every launch

  void* args[] = {(void*)&X, (void*)&Wih, (void*)&Whh, (void*)&bih, (void*)&bhh,
                  (void*)&out, (void*)&flags, (void*)&h1r, (void*)&h2r};
  hipLaunchCooperativeKernel((void*)lstm_kern, dim3(NWG), dim3(128), args, 0, stream);
}